// Round 1
// baseline (1006.874 us; speedup 1.0000x reference)
//
#include <hip/hip_runtime.h>
#include <hip/hip_bf16.h>

#define NTOT 262144
#define BN   64
#define NT   512

// out layout: s_dash [N][256] then V_dash [N][32][3]
__global__ __launch_bounds__(NT, 2)
void gvp_kernel(const float* __restrict__ s,
                const float* __restrict__ V,
                const float* __restrict__ Wh,
                const float* __restrict__ Wmu,
                const float* __restrict__ Wmw,
                const float* __restrict__ Wmb,
                const float* __restrict__ Wgw,
                const float* __restrict__ Wgb,
                float* __restrict__ out)
{
    // LDS plan (bytes):
    //   sWh   32x33 f32          4224   (pad +1: (h+v)%32 conflict-free)
    //   sWmu  32x33 f32          4224
    //   sVh   64x32x3 f32       24576   (V_h; reused at end for V_dash restage)
    //   sShG  64x32 f32          8192   (s_h; reused as gate)
    //   sX    64x20 f32          5120   (s K-chunk, pad 16->20 keeps f4 align)
    //   sPlusVt 64x256 f32      65536   (V tile first, then sigmoid(s_m))
    //   sWu   32x260 f32        33280   (W_m_w chunk [16][260], then W_g [32][260])
    // total ~145 KB <= 160 KB -> 1 block/CU, 8 waves
    __shared__ __attribute__((aligned(16))) float sWh[32*33];
    __shared__ __attribute__((aligned(16))) float sWmu[32*33];
    __shared__ __attribute__((aligned(16))) float sVh[BN*96];
    __shared__ __attribute__((aligned(16))) float sShG[BN*32];
    __shared__ __attribute__((aligned(16))) float sX[BN*20];
    __shared__ __attribute__((aligned(16))) float sPlusVt[BN*256];
    __shared__ __attribute__((aligned(16))) float sWu[32*260];

    const int t  = threadIdx.x;
    const int n0 = blockIdx.x * BN;

    // ---------------- stage Wh, Wmu, V tile ----------------
    #pragma unroll
    for (int i = 0; i < 2; ++i) {
        int idx = t + i*NT;              // 0..1023
        int r = idx >> 5, c = idx & 31;
        sWh [r*33 + c] = Wh [idx];
        sWmu[r*33 + c] = Wmu[idx];
    }
    #pragma unroll
    for (int i = 0; i < 12; ++i) {
        int idx = t + i*NT;              // 0..6143  ([n][v][c] flat)
        sPlusVt[idx] = V[(size_t)n0*96 + idx];
    }
    __syncthreads();

    // ---------------- phase A: V_h = Wh@V, s_h = max(|V_h|,eps) ----------------
    #pragma unroll
    for (int i = 0; i < 4; ++i) {
        int p = t + i*NT;                // 0..2047
        int n = p >> 5, h = p & 31;
        float a0 = 0.f, a1 = 0.f, a2 = 0.f;
        const float* vt = &sPlusVt[n*96];
        #pragma unroll
        for (int v = 0; v < 32; ++v) {
            float w = sWh[h*33 + v];
            a0 = fmaf(w, vt[v*3+0], a0);
            a1 = fmaf(w, vt[v*3+1], a1);
            a2 = fmaf(w, vt[v*3+2], a2);
        }
        sVh[n*96 + h*3 + 0] = a0;
        sVh[n*96 + h*3 + 1] = a1;
        sVh[n*96 + h*3 + 2] = a2;
        float nrm = sqrtf(a0*a0 + a1*a1 + a2*a2);
        sShG[n*32 + h] = fmaxf(nrm, 1e-4f);
    }
    __syncthreads();

    // ---------------- phase B: s_m = [s|s_h] @ Wmw^T ----------------
    // thread (tm,tn): tm=t&63 -> m = tm*4..+3 ; tn=t>>6 -> n = tn*8..+7
    const int tm = t & 63;
    const int tn = t >> 6;
    float acc[4][8];
    #pragma unroll
    for (int a = 0; a < 4; ++a)
        #pragma unroll
        for (int b = 0; b < 8; ++b) acc[a][b] = 0.f;

    for (int kc = 0; kc < 18; ++kc) {    // 16 chunks from s, 2 from s_h
        // stage W chunk: [16 k][260 pad] ; global f4 reads, scattered b32 writes (2-way max)
        #pragma unroll
        for (int i = 0; i < 2; ++i) {
            int flat = t + i*NT;         // 0..1023
            int m = flat >> 2, k4 = flat & 3;
            float4 w4 = *(const float4*)&Wmw[m*288 + kc*16 + k4*4];
            sWu[(k4*4+0)*260 + m] = w4.x;
            sWu[(k4*4+1)*260 + m] = w4.y;
            sWu[(k4*4+2)*260 + m] = w4.z;
            sWu[(k4*4+3)*260 + m] = w4.w;
        }
        if (kc < 16) {
            // stage s chunk: [64 n][20 pad]
            if (t < 256) {
                int n = t >> 2, k4 = t & 3;
                float4 x4 = *(const float4*)&s[(size_t)(n0+n)*256 + kc*16 + k4*4];
                *(float4*)&sX[n*20 + k4*4] = x4;
            }
        }
        __syncthreads();

        const float* xp;
        int xs;
        if (kc < 16) { xp = sX  + tn*8*20;                     xs = 20; }
        else         { xp = sShG + tn*8*32 + (kc-16)*16;       xs = 32; }

        #pragma unroll
        for (int k = 0; k < 16; ++k) {
            float4 w = *(const float4*)&sWu[k*260 + tm*4];  // lane-consecutive 16B: conflict-free
            #pragma unroll
            for (int j = 0; j < 8; ++j) {
                float x = xp[j*xs + k];                     // wave-uniform: broadcast
                acc[0][j] = fmaf(w.x, x, acc[0][j]);
                acc[1][j] = fmaf(w.y, x, acc[1][j]);
                acc[2][j] = fmaf(w.z, x, acc[2][j]);
                acc[3][j] = fmaf(w.w, x, acc[3][j]);
            }
        }
        __syncthreads();
    }

    // epilogue B: bias, relu -> global, sigmoid -> sPlusVt (V tile is dead)
    {
        float4 bias = *(const float4*)&Wmb[tm*4];
        #pragma unroll
        for (int j = 0; j < 8; ++j) {
            int n = tn*8 + j;
            float m0 = acc[0][j] + bias.x;
            float m1 = acc[1][j] + bias.y;
            float m2 = acc[2][j] + bias.z;
            float m3 = acc[3][j] + bias.w;
            float4 sd;
            sd.x = fmaxf(m0, 0.f); sd.y = fmaxf(m1, 0.f);
            sd.z = fmaxf(m2, 0.f); sd.w = fmaxf(m3, 0.f);
            *(float4*)&out[(size_t)(n0+n)*256 + tm*4] = sd;
            float4 sp;
            sp.x = 1.f/(1.f + __expf(-m0));
            sp.y = 1.f/(1.f + __expf(-m1));
            sp.z = 1.f/(1.f + __expf(-m2));
            sp.w = 1.f/(1.f + __expf(-m3));
            *(float4*)&sPlusVt[n*256 + tm*4] = sp;
        }
    }

    // stage W_g into sWu (W chunk dead): [32 gm][260 pad]
    #pragma unroll
    for (int i = 0; i < 16; ++i) {
        int flat = t + i*NT;             // 0..8191
        int gm = flat >> 8, m = flat & 255;
        sWu[gm*260 + m] = Wgw[flat];
    }
    __syncthreads();

    // ---------------- phase C: gate = sigmoid(sigmoid(s_m) @ Wgw^T + b) ----------------
    {
        const int gm   = t & 31;
        const int half = t >> 5;         // 0..15 -> 4 nodes each
        float ga[4];
        float gb = Wgb[gm];
        ga[0] = ga[1] = ga[2] = ga[3] = gb;
        #pragma unroll 8
        for (int m4 = 0; m4 < 64; ++m4) {
            float4 w = *(const float4*)&sWu[gm*260 + m4*4];
            #pragma unroll
            for (int i = 0; i < 4; ++i) {
                int n = half*4 + i;
                float4 x = *(const float4*)&sPlusVt[n*256 + m4*4];  // 2-way broadcast
                ga[i] = fmaf(w.x, x.x, ga[i]);
                ga[i] = fmaf(w.y, x.y, ga[i]);
                ga[i] = fmaf(w.z, x.z, ga[i]);
                ga[i] = fmaf(w.w, x.w, ga[i]);
            }
        }
        __syncthreads();                  // everyone done reading s_h region? (sShG reused below)
        #pragma unroll
        for (int i = 0; i < 4; ++i) {
            int n = half*4 + i;
            sShG[n*32 + gm] = 1.f/(1.f + __expf(-ga[i]));   // gate overwrites s_h
        }
    }
    __syncthreads();

    // ---------------- phase D: V_mu = Wmu@V_h ; V_dash = gate * V_mu ----------------
    float vd[4][3];
    #pragma unroll
    for (int i = 0; i < 4; ++i) {
        int p = t + i*NT;                // 0..2047
        int n = p >> 5, mv = p & 31;
        float a0 = 0.f, a1 = 0.f, a2 = 0.f;
        #pragma unroll
        for (int h = 0; h < 32; ++h) {
            float w = sWmu[mv*33 + h];
            const float* vp = &sVh[n*96 + h*3];
            a0 = fmaf(w, vp[0], a0);
            a1 = fmaf(w, vp[1], a1);
            a2 = fmaf(w, vp[2], a2);
        }
        float g = sShG[n*32 + mv];
        vd[i][0] = g*a0; vd[i][1] = g*a1; vd[i][2] = g*a2;
    }
    __syncthreads();
    // restage V_dash into sVh (now dead) for coalesced f4 stores
    #pragma unroll
    for (int i = 0; i < 4; ++i) {
        int p = t + i*NT;
        int n = p >> 5, mv = p & 31;
        sVh[n*96 + mv*3 + 0] = vd[i][0];
        sVh[n*96 + mv*3 + 1] = vd[i][1];
        sVh[n*96 + mv*3 + 2] = vd[i][2];
    }
    __syncthreads();
    {
        const size_t VBASE = (size_t)NTOT * 256;
        #pragma unroll
        for (int i = 0; i < 3; ++i) {
            int f4 = t + i*NT;           // 0..1535
            float4 v4 = *(const float4*)&sVh[f4*4];
            *(float4*)&out[VBASE + (size_t)n0*96 + f4*4] = v4;
        }
    }
}

extern "C" void kernel_launch(void* const* d_in, const int* in_sizes, int n_in,
                              void* d_out, int out_size, void* d_ws, size_t ws_size,
                              hipStream_t stream) {
    const float* s   = (const float*)d_in[0];
    const float* V   = (const float*)d_in[1];
    const float* Wh  = (const float*)d_in[2];
    const float* Wmu = (const float*)d_in[3];
    const float* Wmw = (const float*)d_in[4];
    const float* Wmb = (const float*)d_in[5];
    const float* Wgw = (const float*)d_in[6];
    const float* Wgb = (const float*)d_in[7];
    float* out = (float*)d_out;

    dim3 grid(NTOT / BN);   // 4096
    dim3 block(NT);         // 512
    gvp_kernel<<<grid, block, 0, stream>>>(s, V, Wh, Wmu, Wmw, Wmb, Wgw, Wgb, out);
}

// Round 2
// 273.685 us; speedup vs baseline: 3.6790x; 3.6790x over previous
//
#include <hip/hip_runtime.h>

#define NTOT 262144
#define BN   32
#define NT   256
#define SXS  296     // sX row stride in shorts (288 + 8 pad -> optimal b128 bank spread)

typedef __attribute__((ext_vector_type(8))) short bf16x8;
typedef __attribute__((ext_vector_type(4))) float f32x4;

static __device__ __forceinline__ unsigned short f2b(float x) {
    union { float f; unsigned u; } c; c.f = x;
    unsigned r = c.u + 0x7FFFu + ((c.u >> 16) & 1u);   // RNE
    return (unsigned short)(r >> 16);
}

static __device__ __forceinline__ void glds16(const unsigned short* g, void* l) {
    __builtin_amdgcn_global_load_lds(
        (const __attribute__((address_space(1))) void*)g,
        (__attribute__((address_space(3))) void*)l, 16, 0, 0);
}

// pack W_m_w f32 [256][288] -> bf16, 9 chunks of [256 out][32 k], k-XOR-swizzled
// (swizzle on short index: kk ^= ((out>>1)&3)<<3) so linear global_load_lds staging
// yields a conflict-free B-frag ds_read_b128 pattern.
__global__ void pack_wmw(const float* __restrict__ Wmw, unsigned short* __restrict__ wp) {
    int t = blockIdx.x * 256 + threadIdx.x;
    if (t >= 256 * 288) return;
    int o = t / 288, k = t % 288;
    int c = k >> 5, kk = k & 31;
    int kks = kk ^ (((o >> 1) & 3) << 3);
    wp[c * 8192 + o * 32 + kks] = f2b(Wmw[t]);
}

template<int USE_WS>
__global__ __launch_bounds__(NT, 2)
void gvp_main(const float* __restrict__ s, const float* __restrict__ V,
              const float* __restrict__ Wh, const float* __restrict__ Wmu,
              const float* __restrict__ Wmw, const float* __restrict__ Wmb,
              const float* __restrict__ Wgw, const float* __restrict__ Wgb,
              const unsigned short* __restrict__ wpack,
              float* __restrict__ out)
{
    // LDS map (77,824 B -> 2 blocks/CU):
    //  [0      , 18944) sX    : bf16 X [32][296]  (s cols 0..255, s_h cols 256..287;
    //                           later sigmoid(s_m) cols 0..255; finally f32 V_dash scratch)
    //  [18944  , 52224) sW    : W chunk double-buf (2x16384) / relu f32 [32][260] / Wg bf16 [32][264]
    //  [52224  , 64512) sV    : V tile f32 [32][96], then V_h f32 [32][96]
    //  [64512  , 69120) sWh   : f32 [32][36]
    //  [69120  , 73728) sWmu  : f32 [32][36]
    //  [73728  , 77824) sGate : f32 [32][32]
    __shared__ __attribute__((aligned(16))) char smem[77824];
    unsigned short* sX   = (unsigned short*)(smem + 0);
    char*           sW   = smem + 18944;
    float*          sV   = (float*)(smem + 52224);
    float*          sWh  = (float*)(smem + 64512);
    float*          sWmu = (float*)(smem + 69120);
    float*          sGate= (float*)(smem + 73728);

    const int t  = threadIdx.x;
    const int w  = t >> 6, l = t & 63;
    const int fr = l & 15, fq = l >> 4;
    const int n0 = blockIdx.x * BN;

    // ---------------- initial staging ----------------
    // s -> sX bf16 (per wave: one node/iter, 1 KB contiguous global read, 512 B contiguous LDS write)
    #pragma unroll
    for (int i = 0; i < 8; ++i) {
        int n = i * 4 + w;
        float4 x4 = *(const float4*)&s[(size_t)(n0 + n) * 256 + 4 * l];
        ushort4 h4; h4.x = f2b(x4.x); h4.y = f2b(x4.y); h4.z = f2b(x4.z); h4.w = f2b(x4.w);
        *(ushort4*)&sX[n * SXS + 4 * l] = h4;
    }
    // V -> sV f32 (contiguous)
    #pragma unroll
    for (int i = 0; i < 3; ++i) {
        int f = i * NT + t;
        *(float4*)&sV[f * 4] = *(const float4*)&V[(size_t)n0 * 96 + f * 4];
    }
    // Wh, Wmu -> padded [32][36]
    {
        int h = t >> 3, v4 = t & 7;
        *(float4*)&sWh[h * 36 + v4 * 4]  = *(const float4*)&Wh[h * 32 + v4 * 4];
        *(float4*)&sWmu[h * 36 + v4 * 4] = *(const float4*)&Wmu[h * 32 + v4 * 4];
    }
    if (USE_WS) {   // issue W chunk 0 into buf0; latency hides under staging+phase A
        const unsigned short* src = wpack + (w * 4) * 512;
        char* dst = sW + (w * 4) * 1024;
        #pragma unroll
        for (int i = 0; i < 4; ++i) glds16(src + i * 512 + l * 8, dst + i * 1024);
    }
    __syncthreads();

    // ---------------- phase A: V_h = Wh@V (f32), s_h = max(|V_h|,eps) -> bf16 X cols 256.. ----
    float vh[4][3];
    #pragma unroll
    for (int i = 0; i < 4; ++i) {
        int p = i * NT + t;
        int n = p >> 5, h = p & 31;
        const float4* vt4 = (const float4*)&sV[n * 96];
        const float4* wh4 = (const float4*)&sWh[h * 36];
        float a0 = 0.f, a1 = 0.f, a2 = 0.f;
        #pragma unroll
        for (int v4 = 0; v4 < 8; ++v4) {
            float4 wv = wh4[v4];
            float4 p0 = vt4[v4 * 3 + 0], p1 = vt4[v4 * 3 + 1], p2 = vt4[v4 * 3 + 2];
            a0 = fmaf(wv.x, p0.x, a0); a1 = fmaf(wv.x, p0.y, a1); a2 = fmaf(wv.x, p0.z, a2);
            a0 = fmaf(wv.y, p0.w, a0); a1 = fmaf(wv.y, p1.x, a1); a2 = fmaf(wv.y, p1.y, a2);
            a0 = fmaf(wv.z, p1.z, a0); a1 = fmaf(wv.z, p1.w, a1); a2 = fmaf(wv.z, p2.x, a2);
            a0 = fmaf(wv.w, p2.y, a0); a1 = fmaf(wv.w, p2.z, a1); a2 = fmaf(wv.w, p2.w, a2);
        }
        vh[i][0] = a0; vh[i][1] = a1; vh[i][2] = a2;
        float nrm = sqrtf(fmaf(a0, a0, fmaf(a1, a1, a2 * a2)));
        sX[n * SXS + 256 + h] = f2b(fmaxf(nrm, 1e-4f));
    }
    __syncthreads();            // all V-tile reads done -> safe to overwrite sV with V_h
    #pragma unroll
    for (int i = 0; i < 4; ++i) {
        int p = i * NT + t;
        int n = p >> 5, h = p & 31;
        sV[n * 96 + h * 3 + 0] = vh[i][0];
        sV[n * 96 + h * 3 + 1] = vh[i][1];
        sV[n * 96 + h * 3 + 2] = vh[i][2];
    }

    // ---------------- main GEMM: s_m = [s|s_h] @ Wmw^T via MFMA ----------------
    // wave w: both M-tiles (nodes 0..15,16..31), N-tiles j -> out cols w*64 + j*16 + fr
    f32x4 acc[2][4];
    #pragma unroll
    for (int mt = 0; mt < 2; ++mt)
        #pragma unroll
        for (int j = 0; j < 4; ++j) acc[mt][j] = (f32x4){0.f, 0.f, 0.f, 0.f};

    for (int ks = 0; ks < 9; ++ks) {
        char* buf = sW + (ks & 1) * 16384;
        if (USE_WS) {
            if (ks < 8) {       // issue next chunk early; drained by end-of-iter barrier
                const unsigned short* src = wpack + (ks + 1) * 8192 + (w * 4) * 512;
                char* dst = sW + ((ks + 1) & 1) * 16384 + (w * 4) * 1024;
                #pragma unroll
                for (int i = 0; i < 4; ++i) glds16(src + i * 512 + l * 8, dst + i * 1024);
            }
        } else {                // fallback: cvt-stage from f32, single buffer
            buf = sW;
            __syncthreads();
            #pragma unroll
            for (int i = 0; i < 8; ++i) {
                int flat = i * NT + t;
                int o = flat >> 3, k4 = flat & 7;
                float4 w4 = *(const float4*)&Wmw[o * 288 + ks * 32 + k4 * 4];
                ushort4 h4; h4.x = f2b(w4.x); h4.y = f2b(w4.y); h4.z = f2b(w4.z); h4.w = f2b(w4.w);
                int ko = (k4 * 4) ^ (((o >> 1) & 3) << 3);
                *(ushort4*)((unsigned short*)buf + o * 32 + ko) = h4;
            }
            __syncthreads();
        }
        const unsigned short* bw = (const unsigned short*)buf;
        bf16x8 a[2], b[4];
        #pragma unroll
        for (int mt = 0; mt < 2; ++mt)
            a[mt] = *(const bf16x8*)&sX[(mt * 16 + fr) * SXS + ks * 32 + fq * 8];
        #pragma unroll
        for (int j = 0; j < 4; ++j) {
            int o = w * 64 + j * 16 + fr;
            b[j] = *(const bf16x8*)&bw[o * 32 + ((fq * 8) ^ (((o >> 1) & 3) << 3))];
        }
        #pragma unroll
        for (int mt = 0; mt < 2; ++mt)
            #pragma unroll
            for (int j = 0; j < 4; ++j)
                acc[mt][j] = __builtin_amdgcn_mfma_f32_16x16x32_bf16(a[mt], b[j], acc[mt][j], 0, 0, 0);
        if (USE_WS) __syncthreads();
    }
    if (!USE_WS) __syncthreads();

    // ---------------- epilogue: bias+relu -> sW f32; sigmoid -> sX bf16 ----------------
    float* sRel = (float*)sW;
    #pragma unroll
    for (int mt = 0; mt < 2; ++mt) {
        #pragma unroll
        for (int j = 0; j < 4; ++j) {
            int col = w * 64 + j * 16 + fr;
            float bias = Wmb[col];
            #pragma unroll
            for (int r = 0; r < 4; ++r) {
                int node = mt * 16 + fq * 4 + r;
                float m = acc[mt][j][r] + bias;
                sRel[node * 260 + col] = fmaxf(m, 0.f);
                sX[node * SXS + col] = f2b(1.f / (1.f + __expf(-m)));
            }
        }
    }
    __syncthreads();

    // ---------------- store s_dash (coalesced f4) ----------------
    #pragma unroll
    for (int i = 0; i < 8; ++i) {
        int n = i * 4 + w;
        float4 v4 = *(const float4*)&sRel[n * 260 + 4 * l];
        *(float4*)&out[(size_t)(n0 + n) * 256 + 4 * l] = v4;
    }
    __syncthreads();

    // ---------------- stage Wg f32->bf16 padded [32][264] ----------------
    unsigned short* sWg = (unsigned short*)sW;
    #pragma unroll
    for (int i = 0; i < 8; ++i) {
        int flat = i * NT + t;
        int gm = flat >> 6, k4 = flat & 63;
        float4 w4 = *(const float4*)&Wgw[gm * 256 + k4 * 4];
        ushort4 h4; h4.x = f2b(w4.x); h4.y = f2b(w4.y); h4.z = f2b(w4.z); h4.w = f2b(w4.w);
        *(ushort4*)&sWg[gm * 264 + k4 * 4] = h4;
    }
    __syncthreads();

    // ---------------- gate GEMM: sigmoid(s_m) @ Wgw^T -> sigmoid -> sGate ----------------
    {
        const int mt = w & 1, nt = w >> 1;
        f32x4 g = (f32x4){0.f, 0.f, 0.f, 0.f};
        #pragma unroll
        for (int ks = 0; ks < 8; ++ks) {
            bf16x8 a = *(const bf16x8*)&sX[(mt * 16 + fr) * SXS + ks * 32 + fq * 8];
            bf16x8 b = *(const bf16x8*)&sWg[(nt * 16 + fr) * 264 + ks * 32 + fq * 8];
            g = __builtin_amdgcn_mfma_f32_16x16x32_bf16(a, b, g, 0, 0, 0);
        }
        int mo = nt * 16 + fr;
        float gb = Wgb[mo];
        #pragma unroll
        for (int r = 0; r < 4; ++r) {
            int node = mt * 16 + fq * 4 + r;
            sGate[node * 32 + mo] = 1.f / (1.f + __expf(-(g[r] + gb)));
        }
    }
    __syncthreads();

    // ---------------- phase D: V_mu = Wmu@V_h (f32), gate, scratch, store ----------------
    float* sc = (float*)smem;   // sX region dead -> f32 V_dash scratch [32][96]
    #pragma unroll
    for (int i = 0; i < 4; ++i) {
        int p = i * NT + t;
        int n = p >> 5, m = p & 31;
        const float4* vt4 = (const float4*)&sV[n * 96];
        const float4* wm4 = (const float4*)&sWmu[m * 36];
        float a0 = 0.f, a1 = 0.f, a2 = 0.f;
        #pragma unroll
        for (int v4 = 0; v4 < 8; ++v4) {
            float4 wv = wm4[v4];
            float4 p0 = vt4[v4 * 3 + 0], p1 = vt4[v4 * 3 + 1], p2 = vt4[v4 * 3 + 2];
            a0 = fmaf(wv.x, p0.x, a0); a1 = fmaf(wv.x, p0.y, a1); a2 = fmaf(wv.x, p0.z, a2);
            a0 = fmaf(wv.y, p0.w, a0); a1 = fmaf(wv.y, p1.x, a1); a2 = fmaf(wv.y, p1.y, a2);
            a0 = fmaf(wv.z, p1.z, a0); a1 = fmaf(wv.z, p1.w, a1); a2 = fmaf(wv.z, p2.x, a2);
            a0 = fmaf(wv.w, p2.y, a0); a1 = fmaf(wv.w, p2.z, a1); a2 = fmaf(wv.w, p2.w, a2);
        }
        float g = sGate[n * 32 + m];
        sc[n * 96 + m * 3 + 0] = g * a0;
        sc[n * 96 + m * 3 + 1] = g * a1;
        sc[n * 96 + m * 3 + 2] = g * a2;
    }
    __syncthreads();
    const size_t VBASE = (size_t)NTOT * 256;
    #pragma unroll
    for (int i = 0; i < 3; ++i) {
        int f = i * NT + t;
        *(float4*)&out[VBASE + (size_t)n0 * 96 + f * 4] = *(const float4*)&sc[f * 4];
    }
}

extern "C" void kernel_launch(void* const* d_in, const int* in_sizes, int n_in,
                              void* d_out, int out_size, void* d_ws, size_t ws_size,
                              hipStream_t stream) {
    const float* s   = (const float*)d_in[0];
    const float* V   = (const float*)d_in[1];
    const float* Wh  = (const float*)d_in[2];
    const float* Wmu = (const float*)d_in[3];
    const float* Wmw = (const float*)d_in[4];
    const float* Wmb = (const float*)d_in[5];
    const float* Wgw = (const float*)d_in[6];
    const float* Wgb = (const float*)d_in[7];
    float* out = (float*)d_out;

    dim3 grid(NTOT / BN);   // 8192
    dim3 block(NT);         // 256

    if (ws_size >= 147456) {
        pack_wmw<<<288, 256, 0, stream>>>(Wmw, (unsigned short*)d_ws);
        gvp_main<1><<<grid, block, 0, stream>>>(s, V, Wh, Wmu, Wmw, Wmb, Wgw, Wgb,
                                                (const unsigned short*)d_ws, out);
    } else {
        gvp_main<0><<<grid, block, 0, stream>>>(s, V, Wh, Wmu, Wmw, Wmb, Wgw, Wgb,
                                                nullptr, out);
    }
}